// Round 1
// baseline (397.952 us; speedup 1.0000x reference)
//
#include <hip/hip_runtime.h>
#include <hip/hip_bf16.h>

#define N_ 384
#define C_ 128
#define M_ (N_*N_)   // 147456 rows (i*384+j)

typedef __attribute__((ext_vector_type(8))) short bf16x8_t;
typedef __attribute__((ext_vector_type(4))) float f32x4_t;
typedef unsigned int u32;
typedef unsigned short u16;

__device__ __forceinline__ u16 f2bf(float f) {
  u32 u = __builtin_bit_cast(u32, f);
  u32 r = (u + 0x7FFFu + ((u >> 16) & 1u)) >> 16;
  return (u16)r;
}
__device__ __forceinline__ float bf2f(u16 h) {
  u32 u = ((u32)h) << 16;
  return __builtin_bit_cast(float, u);
}

// ---------------- prep kernels ----------------
// wcat[n][k], n in [0,384): n<128 -> g_l[k]*Wl[k][n]; n<256 -> g_r[k]*Wr[k][n-128]; else Wg[k][n-256]
// wot[c][h] = Wo[h][c]
__global__ __launch_bounds__(256) void k_prep1(const float* __restrict__ lg, const float* __restrict__ rg,
    const float* __restrict__ Wl, const float* __restrict__ Wr, const float* __restrict__ Wg,
    const float* __restrict__ Wo, u16* __restrict__ wcat, u16* __restrict__ wot) {
  int idx = blockIdx.x*256 + threadIdx.x;
  if (idx < 49152) {
    int n = idx >> 7, k = idx & 127;
    float v;
    if (n < 128)      v = lg[k] * Wl[k*128 + n];
    else if (n < 256) v = rg[k] * Wr[k*128 + (n-128)];
    else              v = Wg[k*128 + (n-256)];
    wcat[idx] = f2bf(v);
  } else {
    int i2 = idx - 49152;           // < 16384
    int c = i2 >> 7, h = i2 & 127;
    wot[i2] = f2bf(Wo[h*128 + c]);
  }
}

// bcat[n]: folded biases (b_l@Wl + bl etc); sg[h] = sum_k Wg[k][h]
__global__ __launch_bounds__(512) void k_prep2(const float* __restrict__ lb, const float* __restrict__ rb,
    const float* __restrict__ Wl, const float* __restrict__ Wr, const float* __restrict__ Wg,
    const float* __restrict__ bl, const float* __restrict__ br, const float* __restrict__ bg,
    float* __restrict__ bcat, float* __restrict__ sg) {
  int t = threadIdx.x;
  if (blockIdx.x == 0) {
    if (t < 384) {
      float s = 0.f;
      if (t < 128)      { for (int k=0;k<128;k++) s += lb[k]*Wl[k*128+t];       s += bl[t];     }
      else if (t < 256) { int h=t-128; for (int k=0;k<128;k++) s += rb[k]*Wr[k*128+h]; s += br[h]; }
      else              { s = bg[t-256]; }
      bcat[t] = s;
    }
  } else {
    if (t < 128) {
      float s = 0.f;
      for (int k=0;k<128;k++) s += Wg[k*128+t];
      sg[t] = s;
    }
  }
}

// ---------------- K1a: LN stats + xhat (bf16) ----------------
__global__ __launch_bounds__(256) void k_ln(const float* __restrict__ pair,
    u32* __restrict__ xhat, float* __restrict__ mu_, float* __restrict__ rstd_) {
  int wave = threadIdx.x >> 6, lane = threadIdx.x & 63;
  int row = blockIdx.x*4 + wave;
  const float2* p2 = (const float2*)(pair + (size_t)row*128);
  float2 v = p2[lane];
  float s = v.x + v.y;
  float q = v.x*v.x + v.y*v.y;
  for (int m=1; m<64; m<<=1) { s += __shfl_xor(s,m,64); q += __shfl_xor(q,m,64); }
  float mu = s * (1.f/128.f);
  float var = q*(1.f/128.f) - mu*mu;
  float rstd = rsqrtf(var + 1e-5f);
  if (lane==0) { mu_[row]=mu; rstd_[row]=rstd; }
  u16 a = f2bf((v.x-mu)*rstd), b = f2bf((v.y-mu)*rstd);
  xhat[(size_t)row*64 + lane] = (u32)a | ((u32)b<<16);
}

#define LDA 72   // bf16 per row of staged 64-wide K-chunk tiles (pad breaks 128B stride)
#define LDT 136  // bf16 per row of transpose-out tile

// ---------------- K1b: projections GEMM + transposed stores ----------------
__global__ __launch_bounds__(256) void k_proj(const u16* __restrict__ xhat, const u16* __restrict__ wcat,
    const float* __restrict__ bcat, const float* __restrict__ sg,
    const float* __restrict__ mu_, const float* __restrict__ rstd_,
    u16* __restrict__ left_t, u16* __restrict__ right_t, u16* __restrict__ gate_t) {
  __shared__ u16 smem[2*128*LDA];   // 36864 B
  u16* At = smem;
  u16* Bt = smem + 128*LDA;
  int bx = blockIdx.x;
  int nb = bx % 3;                  // which n-block (0=left,1=right,2=gate)
  int r0 = (bx / 3) * 128;
  int t = threadIdx.x;
  int w = t >> 6, lane = t & 63;
  int q = lane >> 4, nl = lane & 15;
  f32x4_t acc[2][8] = {};
  for (int kb = 0; kb < 128; kb += 64) {
    { // stage A chunk: xhat[r0+rr][kb..kb+63]
      int rr = t >> 1, half = t & 1;
      const u16* gp = xhat + (size_t)(r0+rr)*128 + kb + half*32;
      u16* lp = At + rr*LDA + half*32;
      for (int i=0;i<4;i++) ((uint4*)lp)[i] = ((const uint4*)gp)[i];
    }
    { // stage B chunk: wcat[nb*128+n][kb..kb+63]  (already [n][k]-major)
      int n = t >> 1, half = t & 1;
      const u16* gp = wcat + (size_t)(nb*128+n)*128 + kb + half*32;
      u16* lp = Bt + n*LDA + half*32;
      for (int i=0;i<4;i++) ((uint4*)lp)[i] = ((const uint4*)gp)[i];
    }
    __syncthreads();
    int mbase = w*32;
    for (int ks = 0; ks < 2; ks++) {
      int kel = ks*32 + q*8;
      bf16x8_t a[2], b[8];
      for (int tm=0;tm<2;tm++) a[tm] = *(const bf16x8_t*)(At + (mbase + tm*16 + nl)*LDA + kel);
      for (int tn=0;tn<8;tn++) b[tn] = *(const bf16x8_t*)(Bt + (tn*16 + nl)*LDA + kel);
      for (int tm=0;tm<2;tm++)
        for (int tn=0;tn<8;tn++)
          acc[tm][tn] = __builtin_amdgcn_mfma_f32_16x16x32_bf16(a[tm], b[tn], acc[tm][tn], 0,0,0);
    }
    __syncthreads();
  }
  // epilogue: bias / gate-sigmoid, then LDS transpose -> coalesced [h][r] stores
  float invs[2][4] = {}, mus[2][4] = {};
  if (nb == 2) {
    for (int tm=0;tm<2;tm++) for (int p=0;p<4;p++) {
      int r = r0 + w*32 + tm*16 + q*4 + p;
      invs[tm][p] = 1.0f / rstd_[r];
      mus[tm][p] = mu_[r];
    }
  }
  u16* Tt = smem;  // reuse: [n][m], stride LDT (128*136 u16 = 34816 B <= 36864)
  for (int tm=0;tm<2;tm++) for (int tn=0;tn<8;tn++) {
    int n = tn*16 + nl;
    float bias = bcat[nb*128 + n];
    float sgn = (nb==2) ? sg[n] : 0.f;
    for (int p=0;p<4;p++) {
      int m = w*32 + tm*16 + q*4 + p;
      float v = acc[tm][tn][p];
      if (nb == 2) {
        v = v*invs[tm][p] + mus[tm][p]*sgn + bias;
        v = 1.0f / (1.0f + __expf(-v));
      } else {
        v = v + bias;
      }
      Tt[n*LDT + m] = f2bf(v);
    }
  }
  __syncthreads();
  u16* dst = (nb==0) ? left_t : (nb==1) ? right_t : gate_t;
  {
    int n = t >> 1, half = t & 1;
    const u16* lp = Tt + n*LDT + half*64;
    u16* gp = dst + (size_t)n*M_ + r0 + half*64;
    for (int i=0;i<8;i++) ((uint4*)gp)[i] = ((const uint4*)lp)[i];
  }
}

// ---------------- K1c: per-h transpose right_t[h][k][j] -> right_tt[h][j][k] ----------------
#define TLD 66
__global__ __launch_bounds__(256) void k_transpose(const u16* __restrict__ src, u16* __restrict__ dst) {
  __shared__ u16 tile[64*TLD];  // 8448 B
  int bx = blockIdx.x;
  int h = bx / 36, rem = bx % 36;
  int ti = rem / 6, tj = rem % 6;
  int k0 = ti*64, j0 = tj*64;
  int t = threadIdx.x;
  {
    int kk = t >> 2, seg = t & 3;
    const u16* gp = src + (size_t)h*M_ + (size_t)(k0+kk)*N_ + j0 + seg*16;
    uint4 a = ((const uint4*)gp)[0];
    uint4 b = ((const uint4*)gp)[1];
    u32* lp = (u32*)(tile + kk*TLD + seg*16);
    lp[0]=a.x; lp[1]=a.y; lp[2]=a.z; lp[3]=a.w;
    lp[4]=b.x; lp[5]=b.y; lp[6]=b.z; lp[7]=b.w;
  }
  __syncthreads();
  {
    int j = t >> 2, q2 = t & 3;
    u32 outv[8];
    for (int s=0;s<8;s++) {
      int kk = q2*16 + 2*s;
      u32 lo = tile[kk*TLD + j];
      u32 hi = tile[(kk+1)*TLD + j];
      outv[s] = lo | (hi<<16);
    }
    u16* gp = dst + (size_t)h*M_ + (size_t)(j0+j)*N_ + k0 + q2*16;
    ((uint4*)gp)[0] = make_uint4(outv[0],outv[1],outv[2],outv[3]);
    ((uint4*)gp)[1] = make_uint4(outv[4],outv[5],outv[6],outv[7]);
  }
}

// ---------------- K2: triangle einsum per h + gate multiply ----------------
__global__ __launch_bounds__(256) void k_einsum(const u16* __restrict__ left_t, const u16* __restrict__ right_tt,
    const u16* __restrict__ gate_t, u16* __restrict__ og_t) {
  __shared__ u16 smem[2*128*LDA];  // 36864 B
  u16* At = smem; u16* Bt = smem + 128*LDA;
  int bx = blockIdx.x;
  int h = bx / 9; int rem = bx % 9;
  int i0 = (rem/3)*128, j0 = (rem%3)*128;
  const u16* Ag = left_t + (size_t)h*M_;
  const u16* Bg = right_tt + (size_t)h*M_;
  int t = threadIdx.x, w = t>>6, lane = t&63;
  int q = lane>>4, nl = lane&15;
  f32x4_t acc[4][4] = {};
  int m0 = (w&1)*64, n0 = (w>>1)*64;
  for (int kb = 0; kb < N_; kb += 64) {
    {
      int rr = t>>1, half = t&1;
      const u16* gp = Ag + (size_t)(i0+rr)*N_ + kb + half*32;
      u16* lp = At + rr*LDA + half*32;
      for (int i=0;i<4;i++) ((uint4*)lp)[i] = ((const uint4*)gp)[i];
      const u16* gq = Bg + (size_t)(j0+rr)*N_ + kb + half*32;
      u16* lq = Bt + rr*LDA + half*32;
      for (int i=0;i<4;i++) ((uint4*)lq)[i] = ((const uint4*)gq)[i];
    }
    __syncthreads();
    for (int ks=0; ks<2; ks++) {
      int kel = ks*32 + q*8;
      bf16x8_t a[4], b[4];
      for (int tm=0;tm<4;tm++) a[tm] = *(const bf16x8_t*)(At + (m0+tm*16+nl)*LDA + kel);
      for (int tn=0;tn<4;tn++) b[tn] = *(const bf16x8_t*)(Bt + (n0+tn*16+nl)*LDA + kel);
      for (int tm=0;tm<4;tm++)
        for (int tn=0;tn<4;tn++)
          acc[tm][tn] = __builtin_amdgcn_mfma_f32_16x16x32_bf16(a[tm], b[tn], acc[tm][tn], 0,0,0);
    }
    __syncthreads();
  }
  // epilogue: acc -> LDS bf16 [m][n], then gate-multiplied coalesced store
  u16* Ot = smem;  // 128*LDT u16 = 34816 B <= 36864
  for (int tm=0;tm<4;tm++) for (int tn=0;tn<4;tn++) for (int p=0;p<4;p++) {
    int m = m0 + tm*16 + q*4 + p;
    int n = n0 + tn*16 + nl;
    Ot[m*LDT + n] = f2bf(acc[tm][tn][p]);
  }
  __syncthreads();
  {
    int m = t>>1, half = t&1;
    size_t rbase = (size_t)h*M_ + (size_t)(i0+m)*N_ + j0 + half*64;
    const uint4* gg = (const uint4*)(gate_t + rbase);
    const uint4* lo = (const uint4*)(Ot + m*LDT + half*64);
    uint4* od = (uint4*)(og_t + rbase);
    for (int i=0;i<8;i++) {
      uint4 gv = gg[i]; uint4 ov = lo[i];
      u32 ga[4] = {gv.x,gv.y,gv.z,gv.w};
      u32 oa[4] = {ov.x,ov.y,ov.z,ov.w};
      u32 ra[4];
      for (int e=0;e<4;e++) {
        float g0 = bf2f((u16)(ga[e]&0xffffu)), g1 = bf2f((u16)(ga[e]>>16));
        float o0 = bf2f((u16)(oa[e]&0xffffu)), o1 = bf2f((u16)(oa[e]>>16));
        ra[e] = (u32)f2bf(o0*g0) | ((u32)f2bf(o1*g1)<<16);
      }
      od[i] = make_uint4(ra[0],ra[1],ra[2],ra[3]);
    }
  }
}

// ---------------- K3: og @ Wo + bo + pair, rowwise LN, fp32 out ----------------
#define LDW 72
__global__ __launch_bounds__(256) void k_final(const u16* __restrict__ og_t, const u16* __restrict__ wot,
    const float* __restrict__ pair, const float* __restrict__ bo,
    const float* __restrict__ ng, const float* __restrict__ nb_,
    float* __restrict__ out) {
  __shared__ u16 smem[2*128*LDW];  // 36864 B
  u16* At = smem; u16* Wt = smem + 128*LDW;
  int bx = blockIdx.x;
  int r0 = bx * 128;
  int t = threadIdx.x, w = t>>6, lane = t&63;
  int q = lane>>4, nl = lane&15;
  f32x4_t acc[2][8] = {};
  for (int c0 = 0; c0 < 128; c0 += 64) {
    { // stage A[m][h'] transposed from og_t[(c0+h')][r0+m]
      int hh = t>>2, seg = t&3;
      const u16* gp = og_t + (size_t)(c0+hh)*M_ + r0 + seg*32;
      u32 vals[16];
      for (int i=0;i<4;i++) { uint4 v4 = ((const uint4*)gp)[i];
        vals[i*4+0]=v4.x; vals[i*4+1]=v4.y; vals[i*4+2]=v4.z; vals[i*4+3]=v4.w; }
      int base_m = seg*32;
      for (int s=0;s<32;s++) {
        int u = (s + t) & 31;                 // phase rotation spreads LDS banks
        u32 pv = vals[u>>1];
        u16 e = (u&1) ? (u16)(pv>>16) : (u16)(pv & 0xffffu);
        At[(base_m + u)*LDW + hh] = e;
      }
    }
    { // stage Wo chunk: Wt[c][h']
      int c = t>>1, half = t&1;
      const u16* gp = wot + (size_t)c*128 + c0 + half*32;
      u16* lp = Wt + c*LDW + half*32;
      for (int i=0;i<4;i++) ((uint4*)lp)[i] = ((const uint4*)gp)[i];
    }
    __syncthreads();
    int mbase = w*32;
    for (int ks=0; ks<2; ks++) {
      int kel = ks*32 + q*8;
      bf16x8_t a[2], b[8];
      for (int tm=0;tm<2;tm++) a[tm] = *(const bf16x8_t*)(At + (mbase+tm*16+nl)*LDW + kel);
      for (int tn=0;tn<8;tn++) b[tn] = *(const bf16x8_t*)(Wt + (tn*16+nl)*LDW + kel);
      for (int tm=0;tm<2;tm++)
        for (int tn=0;tn<8;tn++)
          acc[tm][tn] = __builtin_amdgcn_mfma_f32_16x16x32_bf16(a[tm], b[tn], acc[tm][tn], 0,0,0);
    }
    __syncthreads();
  }
  // epilogue: residual + bias, transpose-free rowwise LN via 16-lane shfl reduction
  float rsum[2][4], rsq[2][4];
  for (int tm=0;tm<2;tm++) for (int p=0;p<4;p++) { rsum[tm][p]=0.f; rsq[tm][p]=0.f; }
  for (int tm=0;tm<2;tm++) for (int tn=0;tn<8;tn++) {
    int n = tn*16 + nl;
    float bb = bo[n];
    for (int p=0;p<4;p++) {
      int m = w*32 + tm*16 + q*4 + p;
      float v = acc[tm][tn][p] + bb + pair[(size_t)(r0+m)*128 + n];
      acc[tm][tn][p] = v;
      rsum[tm][p] += v;
      rsq[tm][p]  += v*v;
    }
  }
  for (int msk=1; msk<16; msk<<=1) {
    for (int tm=0;tm<2;tm++) for (int p=0;p<4;p++) {
      rsum[tm][p] += __shfl_xor(rsum[tm][p], msk, 64);
      rsq[tm][p]  += __shfl_xor(rsq[tm][p],  msk, 64);
    }
  }
  for (int tm=0;tm<2;tm++) for (int p=0;p<4;p++) {
    float mu = rsum[tm][p] * (1.f/128.f);
    float var = rsq[tm][p]*(1.f/128.f) - mu*mu;
    rsum[tm][p] = mu;
    rsq[tm][p] = rsqrtf(var + 1e-5f);
  }
  for (int tm=0;tm<2;tm++) for (int tn=0;tn<8;tn++) {
    int n = tn*16 + nl;
    float g = ng[n], b2 = nb_[n];
    for (int p=0;p<4;p++) {
      int m = w*32 + tm*16 + q*4 + p;
      out[(size_t)(r0+m)*128 + n] = (acc[tm][tn][p] - rsum[tm][p]) * rsq[tm][p] * g + b2;
    }
  }
}

extern "C" void kernel_launch(void* const* d_in, const int* in_sizes, int n_in,
                              void* d_out, int out_size, void* d_ws, size_t ws_size,
                              hipStream_t stream) {
  (void)in_sizes; (void)n_in; (void)out_size; (void)ws_size;
  const float* pair   = (const float*)d_in[0];
  const float* ln_l_g = (const float*)d_in[1];
  const float* ln_l_b = (const float*)d_in[2];
  const float* ln_r_g = (const float*)d_in[3];
  const float* ln_r_b = (const float*)d_in[4];
  const float* Wl = (const float*)d_in[5];
  const float* bl = (const float*)d_in[6];
  const float* Wr = (const float*)d_in[7];
  const float* br = (const float*)d_in[8];
  const float* Wg = (const float*)d_in[9];
  const float* bg = (const float*)d_in[10];
  const float* Wo = (const float*)d_in[11];
  const float* bo = (const float*)d_in[12];
  const float* n_g = (const float*)d_in[13];
  const float* n_b = (const float*)d_in[14];

  char* ws = (char*)d_ws;
  const size_t SZ = (size_t)M_*128*sizeof(u16);         // 37,748,736 B
  u16*  xhat    = (u16*)(ws);                           // dead after k_proj
  u16*  og_t    = (u16*)(ws);                           // aliases xhat (written in k_einsum)
  u16*  gate_t  = (u16*)(ws + SZ);
  u16*  right_t = (u16*)(ws + 2*SZ);                    // dead after k_transpose
  float* mu_    = (float*)(ws + 3*SZ);
  float* rstd_  = (float*)(ws + 3*SZ + 589824);
  u16*  wcat    = (u16*)(ws + 3*SZ + 2*589824);
  float* bcat   = (float*)(ws + 3*SZ + 2*589824 + 98304);
  float* sgp    = (float*)(ws + 3*SZ + 2*589824 + 98304 + 1536);
  u16*  wot     = (u16*)(ws + 3*SZ + 2*589824 + 98304 + 1536 + 512);

  // left_t / right_tt live in d_out until k_final overwrites it with the result
  u16* left_t   = (u16*)d_out;
  u16* right_tt = (u16*)d_out + (size_t)M_*128;

  k_prep1<<<256, 256, 0, stream>>>(ln_l_g, ln_r_g, Wl, Wr, Wg, Wo, wcat, wot);
  k_prep2<<<2, 512, 0, stream>>>(ln_l_b, ln_r_b, Wl, Wr, Wg, bl, br, bg, bcat, sgp);
  k_ln<<<M_/4, 256, 0, stream>>>(pair, (u32*)xhat, mu_, rstd_);
  k_proj<<<3456, 256, 0, stream>>>(xhat, wcat, bcat, sgp, mu_, rstd_, left_t, right_t, gate_t);
  k_transpose<<<4608, 256, 0, stream>>>(right_t, right_tt);
  k_einsum<<<1152, 256, 0, stream>>>(left_t, right_tt, gate_t, og_t);
  k_final<<<1152, 256, 0, stream>>>(og_t, wot, pair, bo, n_g, n_b, (float*)d_out);
}

// Round 2
// 356.447 us; speedup vs baseline: 1.1164x; 1.1164x over previous
//
#include <hip/hip_runtime.h>
#include <hip/hip_bf16.h>

#define N_ 384
#define C_ 128
#define M_ (N_*N_)   // 147456 rows (i*384+j)

typedef __attribute__((ext_vector_type(8))) short bf16x8_t;
typedef __attribute__((ext_vector_type(4))) float f32x4_t;
typedef unsigned int u32;
typedef unsigned short u16;

__device__ __forceinline__ u16 f2bf(float f) {
  u32 u = __builtin_bit_cast(u32, f);
  u32 r = (u + 0x7FFFu + ((u >> 16) & 1u)) >> 16;
  return (u16)r;
}
__device__ __forceinline__ float bf2f(u16 h) {
  u32 u = ((u32)h) << 16;
  return __builtin_bit_cast(float, u);
}

// ---------------- prep kernels ----------------
__global__ __launch_bounds__(256) void k_prep1(const float* __restrict__ lg, const float* __restrict__ rg,
    const float* __restrict__ Wl, const float* __restrict__ Wr, const float* __restrict__ Wg,
    const float* __restrict__ Wo, u16* __restrict__ wcat, u16* __restrict__ wot) {
  int idx = blockIdx.x*256 + threadIdx.x;
  if (idx < 49152) {
    int n = idx >> 7, k = idx & 127;
    float v;
    if (n < 128)      v = lg[k] * Wl[k*128 + n];
    else if (n < 256) v = rg[k] * Wr[k*128 + (n-128)];
    else              v = Wg[k*128 + (n-256)];
    wcat[idx] = f2bf(v);
  } else {
    int i2 = idx - 49152;           // < 16384
    int c = i2 >> 7, h = i2 & 127;
    wot[i2] = f2bf(Wo[h*128 + c]);
  }
}

__global__ __launch_bounds__(512) void k_prep2(const float* __restrict__ lb, const float* __restrict__ rb,
    const float* __restrict__ Wl, const float* __restrict__ Wr, const float* __restrict__ Wg,
    const float* __restrict__ bl, const float* __restrict__ br, const float* __restrict__ bg,
    float* __restrict__ bcat, float* __restrict__ sg) {
  int t = threadIdx.x;
  if (blockIdx.x == 0) {
    if (t < 384) {
      float s = 0.f;
      if (t < 128)      { for (int k=0;k<128;k++) s += lb[k]*Wl[k*128+t];       s += bl[t];     }
      else if (t < 256) { int h=t-128; for (int k=0;k<128;k++) s += rb[k]*Wr[k*128+h]; s += br[h]; }
      else              { s = bg[t-256]; }
      bcat[t] = s;
    }
  } else {
    if (t < 128) {
      float s = 0.f;
      for (int k=0;k<128;k++) s += Wg[k*128+t];
      sg[t] = s;
    }
  }
}

// ---------------- K1a: LN stats + xhat (bf16) ----------------
__global__ __launch_bounds__(256) void k_ln(const float* __restrict__ pair,
    u32* __restrict__ xhat, float* __restrict__ mu_, float* __restrict__ rstd_) {
  int wave = threadIdx.x >> 6, lane = threadIdx.x & 63;
  int row = blockIdx.x*4 + wave;
  const float2* p2 = (const float2*)(pair + (size_t)row*128);
  float2 v = p2[lane];
  float s = v.x + v.y;
  float q = v.x*v.x + v.y*v.y;
  for (int m=1; m<64; m<<=1) { s += __shfl_xor(s,m,64); q += __shfl_xor(q,m,64); }
  float mu = s * (1.f/128.f);
  float var = q*(1.f/128.f) - mu*mu;
  float rstd = rsqrtf(var + 1e-5f);
  if (lane==0) { mu_[row]=mu; rstd_[row]=rstd; }
  u16 a = f2bf((v.x-mu)*rstd), b = f2bf((v.y-mu)*rstd);
  xhat[(size_t)row*64 + lane] = (u32)a | ((u32)b<<16);
}

#define LDA 72   // bf16 per row of staged 64-wide K-chunk tiles (pad breaks 128B stride)
#define LDT 136  // bf16 per row of transpose-out tile

// ---------------- K1b: projections GEMM + transposed stores ----------------
__global__ __launch_bounds__(256) void k_proj(const u16* __restrict__ xhat, const u16* __restrict__ wcat,
    const float* __restrict__ bcat, const float* __restrict__ sg,
    const float* __restrict__ mu_, const float* __restrict__ rstd_,
    u16* __restrict__ left_t, u16* __restrict__ right_t, u16* __restrict__ gate_t) {
  __shared__ u16 smem[2*128*LDA];   // 36864 B
  u16* At = smem;
  u16* Bt = smem + 128*LDA;
  int bx = blockIdx.x;
  int nb = bx % 3;                  // which n-block (0=left,1=right,2=gate)
  int r0 = (bx / 3) * 128;
  int t = threadIdx.x;
  int w = t >> 6, lane = t & 63;
  int q = lane >> 4, nl = lane & 15;
  f32x4_t acc[2][8] = {};
  for (int kb = 0; kb < 128; kb += 64) {
    { // stage A chunk: xhat[r0+rr][kb..kb+63]
      int rr = t >> 1, half = t & 1;
      const u16* gp = xhat + (size_t)(r0+rr)*128 + kb + half*32;
      u16* lp = At + rr*LDA + half*32;
      for (int i=0;i<4;i++) ((uint4*)lp)[i] = ((const uint4*)gp)[i];
    }
    { // stage B chunk: wcat[nb*128+n][kb..kb+63]  (already [n][k]-major)
      int n = t >> 1, half = t & 1;
      const u16* gp = wcat + (size_t)(nb*128+n)*128 + kb + half*32;
      u16* lp = Bt + n*LDA + half*32;
      for (int i=0;i<4;i++) ((uint4*)lp)[i] = ((const uint4*)gp)[i];
    }
    __syncthreads();
    int mbase = w*32;
    for (int ks = 0; ks < 2; ks++) {
      int kel = ks*32 + q*8;
      bf16x8_t a[2], b[8];
      for (int tm=0;tm<2;tm++) a[tm] = *(const bf16x8_t*)(At + (mbase + tm*16 + nl)*LDA + kel);
      for (int tn=0;tn<8;tn++) b[tn] = *(const bf16x8_t*)(Bt + (tn*16 + nl)*LDA + kel);
      for (int tm=0;tm<2;tm++)
        for (int tn=0;tn<8;tn++)
          acc[tm][tn] = __builtin_amdgcn_mfma_f32_16x16x32_bf16(a[tm], b[tn], acc[tm][tn], 0,0,0);
    }
    __syncthreads();
  }
  // epilogue: bias / gate-sigmoid, then LDS transpose -> coalesced [h][r] stores
  float invs[2][4] = {}, mus[2][4] = {};
  if (nb == 2) {
    for (int tm=0;tm<2;tm++) for (int p=0;p<4;p++) {
      int r = r0 + w*32 + tm*16 + q*4 + p;
      invs[tm][p] = 1.0f / rstd_[r];
      mus[tm][p] = mu_[r];
    }
  }
  u16* Tt = smem;  // reuse: [n][m], stride LDT (128*136 u16 = 34816 B <= 36864)
  for (int tm=0;tm<2;tm++) for (int tn=0;tn<8;tn++) {
    int n = tn*16 + nl;
    float bias = bcat[nb*128 + n];
    float sgn = (nb==2) ? sg[n] : 0.f;
    for (int p=0;p<4;p++) {
      int m = w*32 + tm*16 + q*4 + p;
      float v = acc[tm][tn][p];
      if (nb == 2) {
        v = v*invs[tm][p] + mus[tm][p]*sgn + bias;
        v = 1.0f / (1.0f + __expf(-v));
      } else {
        v = v + bias;
      }
      Tt[n*LDT + m] = f2bf(v);
    }
  }
  __syncthreads();
  u16* dst = (nb==0) ? left_t : (nb==1) ? right_t : gate_t;
  {
    int n = t >> 1, half = t & 1;
    const u16* lp = Tt + n*LDT + half*64;
    u16* gp = dst + (size_t)n*M_ + r0 + half*64;
    for (int i=0;i<8;i++) ((uint4*)gp)[i] = ((const uint4*)lp)[i];
  }
}

// ---------------- K1c: per-h transpose right_t[h][k][j] -> right_tt[h][j][k] ----------------
#define TLD 66
__global__ __launch_bounds__(256) void k_transpose(const u16* __restrict__ src, u16* __restrict__ dst) {
  __shared__ u16 tile[64*TLD];  // 8448 B
  int bx = blockIdx.x;
  int h = bx / 36, rem = bx % 36;
  int ti = rem / 6, tj = rem % 6;
  int k0 = ti*64, j0 = tj*64;
  int t = threadIdx.x;
  {
    int kk = t >> 2, seg = t & 3;
    const u16* gp = src + (size_t)h*M_ + (size_t)(k0+kk)*N_ + j0 + seg*16;
    uint4 a = ((const uint4*)gp)[0];
    uint4 b = ((const uint4*)gp)[1];
    u32* lp = (u32*)(tile + kk*TLD + seg*16);
    lp[0]=a.x; lp[1]=a.y; lp[2]=a.z; lp[3]=a.w;
    lp[4]=b.x; lp[5]=b.y; lp[6]=b.z; lp[7]=b.w;
  }
  __syncthreads();
  {
    int j = t >> 2, q2 = t & 3;
    u32 outv[8];
    for (int s=0;s<8;s++) {
      int kk = q2*16 + 2*s;
      u32 lo = tile[kk*TLD + j];
      u32 hi = tile[(kk+1)*TLD + j];
      outv[s] = lo | (hi<<16);
    }
    u16* gp = dst + (size_t)h*M_ + (size_t)(j0+j)*N_ + k0 + q2*16;
    ((uint4*)gp)[0] = make_uint4(outv[0],outv[1],outv[2],outv[3]);
    ((uint4*)gp)[1] = make_uint4(outv[4],outv[5],outv[6],outv[7]);
  }
}

// ---------------- K2: triangle einsum per h + gate multiply ----------------
__global__ __launch_bounds__(256) void k_einsum(const u16* __restrict__ left_t, const u16* __restrict__ right_tt,
    const u16* __restrict__ gate_t, u16* __restrict__ og_t) {
  __shared__ u16 smem[2*128*LDA];  // 36864 B
  u16* At = smem; u16* Bt = smem + 128*LDA;
  int bx = blockIdx.x;
  int h = bx / 9; int rem = bx % 9;
  int i0 = (rem/3)*128, j0 = (rem%3)*128;
  const u16* Ag = left_t + (size_t)h*M_;
  const u16* Bg = right_tt + (size_t)h*M_;
  int t = threadIdx.x, w = t>>6, lane = t&63;
  int q = lane>>4, nl = lane&15;
  f32x4_t acc[4][4] = {};
  int m0 = (w&1)*64, n0 = (w>>1)*64;
  for (int kb = 0; kb < N_; kb += 64) {
    {
      int rr = t>>1, half = t&1;
      const u16* gp = Ag + (size_t)(i0+rr)*N_ + kb + half*32;
      u16* lp = At + rr*LDA + half*32;
      for (int i=0;i<4;i++) ((uint4*)lp)[i] = ((const uint4*)gp)[i];
      const u16* gq = Bg + (size_t)(j0+rr)*N_ + kb + half*32;
      u16* lq = Bt + rr*LDA + half*32;
      for (int i=0;i<4;i++) ((uint4*)lq)[i] = ((const uint4*)gq)[i];
    }
    __syncthreads();
    for (int ks=0; ks<2; ks++) {
      int kel = ks*32 + q*8;
      bf16x8_t a[4], b[4];
      for (int tm=0;tm<4;tm++) a[tm] = *(const bf16x8_t*)(At + (m0+tm*16+nl)*LDA + kel);
      for (int tn=0;tn<4;tn++) b[tn] = *(const bf16x8_t*)(Bt + (n0+tn*16+nl)*LDA + kel);
      for (int tm=0;tm<4;tm++)
        for (int tn=0;tn<4;tn++)
          acc[tm][tn] = __builtin_amdgcn_mfma_f32_16x16x32_bf16(a[tm], b[tn], acc[tm][tn], 0,0,0);
    }
    __syncthreads();
  }
  // epilogue: acc -> LDS bf16 [m][n], then gate-multiplied coalesced store
  u16* Ot = smem;  // 128*LDT u16 = 34816 B <= 36864
  for (int tm=0;tm<4;tm++) for (int tn=0;tn<4;tn++) for (int p=0;p<4;p++) {
    int m = m0 + tm*16 + q*4 + p;
    int n = n0 + tn*16 + nl;
    Ot[m*LDT + n] = f2bf(acc[tm][tn][p]);
  }
  __syncthreads();
  {
    int m = t>>1, half = t&1;
    size_t rbase = (size_t)h*M_ + (size_t)(i0+m)*N_ + j0 + half*64;
    const uint4* gg = (const uint4*)(gate_t + rbase);
    const uint4* lo = (const uint4*)(Ot + m*LDT + half*64);
    uint4* od = (uint4*)(og_t + rbase);
    for (int i=0;i<8;i++) {
      uint4 gv = gg[i]; uint4 ov = lo[i];
      u32 ga[4] = {gv.x,gv.y,gv.z,gv.w};
      u32 oa[4] = {ov.x,ov.y,ov.z,ov.w};
      u32 ra[4];
      for (int e=0;e<4;e++) {
        float g0 = bf2f((u16)(ga[e]&0xffffu)), g1 = bf2f((u16)(ga[e]>>16));
        float o0 = bf2f((u16)(oa[e]&0xffffu)), o1 = bf2f((u16)(oa[e]>>16));
        ra[e] = (u32)f2bf(o0*g0) | ((u32)f2bf(o1*g1)<<16);
      }
      od[i] = make_uint4(ra[0],ra[1],ra[2],ra[3]);
    }
  }
}

// ---------------- K2b: transpose og_t[h][r] -> og_row[r][h] ----------------
__global__ __launch_bounds__(256) void k_transpose_og(const u16* __restrict__ src, u16* __restrict__ dst) {
  __shared__ u16 tile[64*TLD];  // 8448 B
  int bx = blockIdx.x;
  int h0 = (bx & 1) * 64;
  int r0 = (bx >> 1) * 64;
  int t = threadIdx.x;
  {
    int hh = t >> 2, seg = t & 3;
    const u16* gp = src + (size_t)(h0+hh)*M_ + r0 + seg*16;
    uint4 a = ((const uint4*)gp)[0];
    uint4 b = ((const uint4*)gp)[1];
    u32* lp = (u32*)(tile + hh*TLD + seg*16);
    lp[0]=a.x; lp[1]=a.y; lp[2]=a.z; lp[3]=a.w;
    lp[4]=b.x; lp[5]=b.y; lp[6]=b.z; lp[7]=b.w;
  }
  __syncthreads();
  {
    int r = t >> 2, q2 = t & 3;
    u32 outv[8];
    for (int s=0;s<8;s++) {
      int hh = q2*16 + 2*s;
      u32 lo = tile[hh*TLD + r];
      u32 hi = tile[(hh+1)*TLD + r];
      outv[s] = lo | (hi<<16);
    }
    u16* gp = dst + (size_t)(r0+r)*128 + h0 + q2*16;
    ((uint4*)gp)[0] = make_uint4(outv[0],outv[1],outv[2],outv[3]);
    ((uint4*)gp)[1] = make_uint4(outv[4],outv[5],outv[6],outv[7]);
  }
}

// ---------------- K3: og_row @ Wo + bo + pair, rowwise LN, fp32 out ----------------
#define LDW 72
__global__ __launch_bounds__(256) void k_final(const u16* __restrict__ og_row, const u16* __restrict__ wot,
    const float* __restrict__ pair, const float* __restrict__ bo,
    const float* __restrict__ ng, const float* __restrict__ nb_,
    float* __restrict__ out) {
  __shared__ u16 smem[2*128*LDW];  // 36864 B
  u16* At = smem; u16* Wt = smem + 128*LDW;
  int bx = blockIdx.x;
  int r0 = bx * 128;
  int t = threadIdx.x, w = t>>6, lane = t&63;
  int q = lane>>4, nl = lane&15;
  f32x4_t acc[2][8] = {};
  for (int c0 = 0; c0 < 128; c0 += 64) {
    { // stage A: og_row[r0+rr][c0 .. c0+63] — coalesced, vectorized, no transpose
      int rr = t >> 1, half = t & 1;
      const u16* gp = og_row + (size_t)(r0+rr)*128 + c0 + half*32;
      u16* lp = At + rr*LDW + half*32;
      for (int i=0;i<4;i++) ((uint4*)lp)[i] = ((const uint4*)gp)[i];
    }
    { // stage Wo chunk: Wt[c][h']
      int c = t>>1, half = t&1;
      const u16* gp = wot + (size_t)c*128 + c0 + half*32;
      u16* lp = Wt + c*LDW + half*32;
      for (int i=0;i<4;i++) ((uint4*)lp)[i] = ((const uint4*)gp)[i];
    }
    __syncthreads();
    int mbase = w*32;
    for (int ks=0; ks<2; ks++) {
      int kel = ks*32 + q*8;
      bf16x8_t a[2], b[8];
      for (int tm=0;tm<2;tm++) a[tm] = *(const bf16x8_t*)(At + (mbase+tm*16+nl)*LDW + kel);
      for (int tn=0;tn<8;tn++) b[tn] = *(const bf16x8_t*)(Wt + (tn*16+nl)*LDW + kel);
      for (int tm=0;tm<2;tm++)
        for (int tn=0;tn<8;tn++)
          acc[tm][tn] = __builtin_amdgcn_mfma_f32_16x16x32_bf16(a[tm], b[tn], acc[tm][tn], 0,0,0);
    }
    __syncthreads();
  }
  // epilogue: residual + bias, transpose-free rowwise LN via 16-lane shfl reduction
  float rsum[2][4], rsq[2][4];
  for (int tm=0;tm<2;tm++) for (int p=0;p<4;p++) { rsum[tm][p]=0.f; rsq[tm][p]=0.f; }
  for (int tm=0;tm<2;tm++) for (int tn=0;tn<8;tn++) {
    int n = tn*16 + nl;
    float bb = bo[n];
    for (int p=0;p<4;p++) {
      int m = w*32 + tm*16 + q*4 + p;
      float v = acc[tm][tn][p] + bb + pair[(size_t)(r0+m)*128 + n];
      acc[tm][tn][p] = v;
      rsum[tm][p] += v;
      rsq[tm][p]  += v*v;
    }
  }
  for (int msk=1; msk<16; msk<<=1) {
    for (int tm=0;tm<2;tm++) for (int p=0;p<4;p++) {
      rsum[tm][p] += __shfl_xor(rsum[tm][p], msk, 64);
      rsq[tm][p]  += __shfl_xor(rsq[tm][p],  msk, 64);
    }
  }
  for (int tm=0;tm<2;tm++) for (int p=0;p<4;p++) {
    float mu = rsum[tm][p] * (1.f/128.f);
    float var = rsq[tm][p]*(1.f/128.f) - mu*mu;
    rsum[tm][p] = mu;
    rsq[tm][p] = rsqrtf(var + 1e-5f);
  }
  for (int tm=0;tm<2;tm++) for (int tn=0;tn<8;tn++) {
    int n = tn*16 + nl;
    float g = ng[n], b2 = nb_[n];
    for (int p=0;p<4;p++) {
      int m = w*32 + tm*16 + q*4 + p;
      out[(size_t)(r0+m)*128 + n] = (acc[tm][tn][p] - rsum[tm][p]) * rsq[tm][p] * g + b2;
    }
  }
}

extern "C" void kernel_launch(void* const* d_in, const int* in_sizes, int n_in,
                              void* d_out, int out_size, void* d_ws, size_t ws_size,
                              hipStream_t stream) {
  (void)in_sizes; (void)n_in; (void)out_size; (void)ws_size;
  const float* pair   = (const float*)d_in[0];
  const float* ln_l_g = (const float*)d_in[1];
  const float* ln_l_b = (const float*)d_in[2];
  const float* ln_r_g = (const float*)d_in[3];
  const float* ln_r_b = (const float*)d_in[4];
  const float* Wl = (const float*)d_in[5];
  const float* bl = (const float*)d_in[6];
  const float* Wr = (const float*)d_in[7];
  const float* br = (const float*)d_in[8];
  const float* Wg = (const float*)d_in[9];
  const float* bg = (const float*)d_in[10];
  const float* Wo = (const float*)d_in[11];
  const float* bo = (const float*)d_in[12];
  const float* n_g = (const float*)d_in[13];
  const float* n_b = (const float*)d_in[14];

  char* ws = (char*)d_ws;
  const size_t SZ = (size_t)M_*128*sizeof(u16);         // 37,748,736 B
  u16*  xhat    = (u16*)(ws);                           // dead after k_proj
  u16*  og_t    = (u16*)(ws);                           // aliases xhat (written in k_einsum)
  u16*  gate_t  = (u16*)(ws + SZ);
  u16*  right_t = (u16*)(ws + 2*SZ);                    // dead after k_transpose
  u16*  og_row  = (u16*)(ws + 2*SZ);                    // aliases right_t (written after einsum)
  float* mu_    = (float*)(ws + 3*SZ);
  float* rstd_  = (float*)(ws + 3*SZ + 589824);
  u16*  wcat    = (u16*)(ws + 3*SZ + 2*589824);
  float* bcat   = (float*)(ws + 3*SZ + 2*589824 + 98304);
  float* sgp    = (float*)(ws + 3*SZ + 2*589824 + 98304 + 1536);
  u16*  wot     = (u16*)(ws + 3*SZ + 2*589824 + 98304 + 1536 + 512);

  // left_t / right_tt live in d_out until k_final overwrites it with the result
  u16* left_t   = (u16*)d_out;
  u16* right_tt = (u16*)d_out + (size_t)M_*128;

  k_prep1<<<256, 256, 0, stream>>>(ln_l_g, ln_r_g, Wl, Wr, Wg, Wo, wcat, wot);
  k_prep2<<<2, 512, 0, stream>>>(ln_l_b, ln_r_b, Wl, Wr, Wg, bl, br, bg, bcat, sgp);
  k_ln<<<M_/4, 256, 0, stream>>>(pair, (u32*)xhat, mu_, rstd_);
  k_proj<<<3456, 256, 0, stream>>>(xhat, wcat, bcat, sgp, mu_, rstd_, left_t, right_t, gate_t);
  k_transpose<<<4608, 256, 0, stream>>>(right_t, right_tt);
  k_einsum<<<1152, 256, 0, stream>>>(left_t, right_tt, gate_t, og_t);
  k_transpose_og<<<4608, 256, 0, stream>>>(og_t, og_row);
  k_final<<<1152, 256, 0, stream>>>(og_row, wot, pair, bo, n_g, n_b, (float*)d_out);
}

// Round 4
// 351.974 us; speedup vs baseline: 1.1306x; 1.0127x over previous
//
#include <hip/hip_runtime.h>
#include <hip/hip_bf16.h>

#define N_ 384
#define C_ 128
#define M_ (N_*N_)   // 147456 rows (i*384+j)

typedef __attribute__((ext_vector_type(8))) short bf16x8_t;
typedef __attribute__((ext_vector_type(4))) float f32x4_t;
typedef unsigned int u32;
typedef unsigned short u16;

__device__ __forceinline__ u16 f2bf(float f) {
  u32 u = __builtin_bit_cast(u32, f);
  u32 r = (u + 0x7FFFu + ((u >> 16) & 1u)) >> 16;
  return (u16)r;
}
__device__ __forceinline__ float bf2f(u16 h) {
  u32 u = ((u32)h) << 16;
  return __builtin_bit_cast(float, u);
}

// ---------------- prep kernels ----------------
__global__ __launch_bounds__(256) void k_prep1(const float* __restrict__ lg, const float* __restrict__ rg,
    const float* __restrict__ Wl, const float* __restrict__ Wr, const float* __restrict__ Wg,
    const float* __restrict__ Wo, u16* __restrict__ wcat, u16* __restrict__ wot) {
  int idx = blockIdx.x*256 + threadIdx.x;
  if (idx < 49152) {
    int n = idx >> 7, k = idx & 127;
    float v;
    if (n < 128)      v = lg[k] * Wl[k*128 + n];
    else if (n < 256) v = rg[k] * Wr[k*128 + (n-128)];
    else              v = Wg[k*128 + (n-256)];
    wcat[idx] = f2bf(v);
  } else {
    int i2 = idx - 49152;           // < 16384
    int c = i2 >> 7, h = i2 & 127;
    wot[i2] = f2bf(Wo[h*128 + c]);
  }
}

__global__ __launch_bounds__(512) void k_prep2(const float* __restrict__ lb, const float* __restrict__ rb,
    const float* __restrict__ Wl, const float* __restrict__ Wr, const float* __restrict__ Wg,
    const float* __restrict__ bl, const float* __restrict__ br, const float* __restrict__ bg,
    float* __restrict__ bcat, float* __restrict__ sg) {
  int t = threadIdx.x;
  if (blockIdx.x == 0) {
    if (t < 384) {
      float s = 0.f;
      if (t < 128)      { for (int k=0;k<128;k++) s += lb[k]*Wl[k*128+t];       s += bl[t];     }
      else if (t < 256) { int h=t-128; for (int k=0;k<128;k++) s += rb[k]*Wr[k*128+h]; s += br[h]; }
      else              { s = bg[t-256]; }
      bcat[t] = s;
    }
  } else {
    if (t < 128) {
      float s = 0.f;
      for (int k=0;k<128;k++) s += Wg[k*128+t];
      sg[t] = s;
    }
  }
}

#define LDK 136  // u16 stride of staged 128-k rows (16B-aligned rows, +8 pad)
#define LDA 72
#define LDT 136
#define TLD 66

// ---------------- K1: fused LN + 3 projections + transposed stores ----------------
// block = 128 rows. LN in-register, xhat bf16 -> LDS (reused for 3 GEMMs).
// B fragments read directly from global wcat (L2-resident, 96 KB).
__global__ __launch_bounds__(256) void k_projln(const float* __restrict__ pair,
    const u16* __restrict__ wcat, const float* __restrict__ bcat, const float* __restrict__ sg,
    u16* __restrict__ left_t, u16* __restrict__ right_t, u16* __restrict__ gate_t) {
  __shared__ u16 At[128*LDK];   // 34816 B
  __shared__ u16 Tt[64*LDK];    // 17408 B
  __shared__ float mu_s[128];
  __shared__ float irs_s[128];
  int r0 = blockIdx.x * 128;
  int t = threadIdx.x, w = t>>6, lane = t&63;
  int q = lane>>4, nl = lane&15;

  // ---- LN phase: 2 threads per row ----
  {
    int rr = t >> 1, half = t & 1;
    const float4* gp = (const float4*)(pair + (size_t)(r0+rr)*128 + half*64);
    float4 v[16];
    #pragma unroll
    for (int i=0;i<16;i++) v[i] = gp[i];
    float s=0.f, qq=0.f;
    #pragma unroll
    for (int i=0;i<16;i++) {
      s  += v[i].x + v[i].y + v[i].z + v[i].w;
      qq += v[i].x*v[i].x + v[i].y*v[i].y + v[i].z*v[i].z + v[i].w*v[i].w;
    }
    s  += __shfl_xor(s, 1, 64);
    qq += __shfl_xor(qq, 1, 64);
    float mu = s * (1.f/128.f);
    float var = qq*(1.f/128.f) - mu*mu;
    float rstd = rsqrtf(var + 1e-5f);
    if (half == 0) { mu_s[rr] = mu; irs_s[rr] = 1.0f/rstd; }
    u32* lp = (u32*)(At + rr*LDK + half*64);
    #pragma unroll
    for (int i=0;i<8;i++) {
      u32 p0 = (u32)f2bf((v[2*i].x-mu)*rstd)   | ((u32)f2bf((v[2*i].y-mu)*rstd)<<16);
      u32 p1 = (u32)f2bf((v[2*i].z-mu)*rstd)   | ((u32)f2bf((v[2*i].w-mu)*rstd)<<16);
      u32 p2 = (u32)f2bf((v[2*i+1].x-mu)*rstd) | ((u32)f2bf((v[2*i+1].y-mu)*rstd)<<16);
      u32 p3 = (u32)f2bf((v[2*i+1].z-mu)*rstd) | ((u32)f2bf((v[2*i+1].w-mu)*rstd)<<16);
      ((uint4*)lp)[i] = make_uint4(p0,p1,p2,p3);
    }
  }
  __syncthreads();

  // per-thread output-row LN params (for gate reconstruction)
  float muv[2][4], irv[2][4];
  #pragma unroll
  for (int tm=0;tm<2;tm++)
    #pragma unroll
    for (int p=0;p<4;p++) {
      int m = w*32 + tm*16 + q*4 + p;
      muv[tm][p] = mu_s[m];
      irv[tm][p] = irs_s[m];
    }

  for (int nb=0; nb<3; nb++) {
    f32x4_t acc[2][8] = {};
    const u16* bbase = wcat + (size_t)(nb*128)*128;
    #pragma unroll
    for (int ks=0; ks<4; ks++) {
      int kel = ks*32 + q*8;
      bf16x8_t a0 = *(const bf16x8_t*)(At + (w*32      + nl)*LDK + kel);
      bf16x8_t a1 = *(const bf16x8_t*)(At + (w*32 + 16 + nl)*LDK + kel);
      #pragma unroll
      for (int tn=0;tn<8;tn++) {
        bf16x8_t b = *(const bf16x8_t*)(bbase + (size_t)(tn*16+nl)*128 + kel);
        acc[0][tn] = __builtin_amdgcn_mfma_f32_16x16x32_bf16(a0, b, acc[0][tn], 0,0,0);
        acc[1][tn] = __builtin_amdgcn_mfma_f32_16x16x32_bf16(a1, b, acc[1][tn], 0,0,0);
      }
    }
    u16* dst = (nb==0) ? left_t : (nb==1) ? right_t : gate_t;
    for (int nhalf=0; nhalf<2; nhalf++) {
      #pragma unroll
      for (int tm=0;tm<2;tm++)
        #pragma unroll
        for (int tn4=0;tn4<4;tn4++) {
          int tn = nhalf*4 + tn4;
          int n = tn*16 + nl;
          float bias = bcat[nb*128 + n];
          float sgn = (nb==2) ? sg[n] : 0.f;
          f32x4_t a4 = acc[tm][tn];
          float o[4];
          #pragma unroll
          for (int p=0;p<4;p++) {
            float v = a4[p];
            if (nb == 2) {
              v = v*irv[tm][p] + muv[tm][p]*sgn + bias;
              v = 1.0f / (1.0f + __expf(-v));
            } else {
              v += bias;
            }
            o[p] = v;
          }
          int m = w*32 + tm*16 + q*4;
          u32* wp = (u32*)(Tt + (tn4*16+nl)*LDK + m);
          wp[0] = (u32)f2bf(o[0]) | ((u32)f2bf(o[1])<<16);
          wp[1] = (u32)f2bf(o[2]) | ((u32)f2bf(o[3])<<16);
        }
      __syncthreads();
      {
        // full row copy: 4 threads/row x 32 u16 (4x uint4) = 128 u16 per row
        int nr = t>>2, q4 = t&3;
        const uint4* lp = (const uint4*)(Tt + nr*LDK + q4*32);
        u16* gp = dst + (size_t)(nhalf*64+nr)*M_ + r0 + q4*32;
        ((uint4*)gp)[0] = lp[0];
        ((uint4*)gp)[1] = lp[1];
        ((uint4*)gp)[2] = lp[2];
        ((uint4*)gp)[3] = lp[3];
      }
      __syncthreads();
    }
  }
}

// ---------------- K1c: per-h transpose right_t[h][k][j] -> right_tt[h][j][k] ----------------
__global__ __launch_bounds__(256) void k_transpose(const u16* __restrict__ src, u16* __restrict__ dst) {
  __shared__ u16 tile[64*TLD];  // 8448 B
  int bx = blockIdx.x;
  int h = bx / 36, rem = bx % 36;
  int ti = rem / 6, tj = rem % 6;
  int k0 = ti*64, j0 = tj*64;
  int t = threadIdx.x;
  {
    int kk = t >> 2, seg = t & 3;
    const u16* gp = src + (size_t)h*M_ + (size_t)(k0+kk)*N_ + j0 + seg*16;
    uint4 a = ((const uint4*)gp)[0];
    uint4 b = ((const uint4*)gp)[1];
    u32* lp = (u32*)(tile + kk*TLD + seg*16);
    lp[0]=a.x; lp[1]=a.y; lp[2]=a.z; lp[3]=a.w;
    lp[4]=b.x; lp[5]=b.y; lp[6]=b.z; lp[7]=b.w;
  }
  __syncthreads();
  {
    int j = t >> 2, q2 = t & 3;
    u32 outv[8];
    for (int s=0;s<8;s++) {
      int kk = q2*16 + 2*s;
      u32 lo = tile[kk*TLD + j];
      u32 hi = tile[(kk+1)*TLD + j];
      outv[s] = lo | (hi<<16);
    }
    u16* gp = dst + (size_t)h*M_ + (size_t)(j0+j)*N_ + k0 + q2*16;
    ((uint4*)gp)[0] = make_uint4(outv[0],outv[1],outv[2],outv[3]);
    ((uint4*)gp)[1] = make_uint4(outv[4],outv[5],outv[6],outv[7]);
  }
}

// ---------------- K2: triangle einsum per h + gate multiply ----------------
__global__ __launch_bounds__(256) void k_einsum(const u16* __restrict__ left_t, const u16* __restrict__ right_tt,
    const u16* __restrict__ gate_t, u16* __restrict__ og_t) {
  __shared__ u16 smem[2*128*LDA];  // 36864 B
  u16* At = smem; u16* Bt = smem + 128*LDA;
  int bx = blockIdx.x;
  int h = bx / 9; int rem = bx % 9;
  int i0 = (rem/3)*128, j0 = (rem%3)*128;
  const u16* Ag = left_t + (size_t)h*M_;
  const u16* Bg = right_tt + (size_t)h*M_;
  int t = threadIdx.x, w = t>>6, lane = t&63;
  int q = lane>>4, nl = lane&15;
  f32x4_t acc[4][4] = {};
  int m0 = (w&1)*64, n0 = (w>>1)*64;
  for (int kb = 0; kb < N_; kb += 64) {
    {
      int rr = t>>1, half = t&1;
      const u16* gp = Ag + (size_t)(i0+rr)*N_ + kb + half*32;
      u16* lp = At + rr*LDA + half*32;
      for (int i=0;i<4;i++) ((uint4*)lp)[i] = ((const uint4*)gp)[i];
      const u16* gq = Bg + (size_t)(j0+rr)*N_ + kb + half*32;
      u16* lq = Bt + rr*LDA + half*32;
      for (int i=0;i<4;i++) ((uint4*)lq)[i] = ((const uint4*)gq)[i];
    }
    __syncthreads();
    for (int ks=0; ks<2; ks++) {
      int kel = ks*32 + q*8;
      bf16x8_t a[4], b[4];
      for (int tm=0;tm<4;tm++) a[tm] = *(const bf16x8_t*)(At + (m0+tm*16+nl)*LDA + kel);
      for (int tn=0;tn<4;tn++) b[tn] = *(const bf16x8_t*)(Bt + (n0+tn*16+nl)*LDA + kel);
      for (int tm=0;tm<4;tm++)
        for (int tn=0;tn<4;tn++)
          acc[tm][tn] = __builtin_amdgcn_mfma_f32_16x16x32_bf16(a[tm], b[tn], acc[tm][tn], 0,0,0);
    }
    __syncthreads();
  }
  // epilogue: acc -> LDS bf16 [m][n], then gate-multiplied coalesced store
  u16* Ot = smem;  // 128*LDT u16 = 34816 B <= 36864
  for (int tm=0;tm<4;tm++) for (int tn=0;tn<4;tn++) for (int p=0;p<4;p++) {
    int m = m0 + tm*16 + q*4 + p;
    int n = n0 + tn*16 + nl;
    Ot[m*LDT + n] = f2bf(acc[tm][tn][p]);
  }
  __syncthreads();
  {
    int m = t>>1, half = t&1;
    size_t rbase = (size_t)h*M_ + (size_t)(i0+m)*N_ + j0 + half*64;
    const uint4* gg = (const uint4*)(gate_t + rbase);
    const uint4* lo = (const uint4*)(Ot + m*LDT + half*64);
    uint4* od = (uint4*)(og_t + rbase);
    for (int i=0;i<8;i++) {
      uint4 gv = gg[i]; uint4 ov = lo[i];
      u32 ga[4] = {gv.x,gv.y,gv.z,gv.w};
      u32 oa[4] = {ov.x,ov.y,ov.z,ov.w};
      u32 ra[4];
      for (int e=0;e<4;e++) {
        float g0 = bf2f((u16)(ga[e]&0xffffu)), g1 = bf2f((u16)(ga[e]>>16));
        float o0 = bf2f((u16)(oa[e]&0xffffu)), o1 = bf2f((u16)(oa[e]>>16));
        ra[e] = (u32)f2bf(o0*g0) | ((u32)f2bf(o1*g1)<<16);
      }
      od[i] = make_uint4(ra[0],ra[1],ra[2],ra[3]);
    }
  }
}

// ---------------- K2b: transpose og_t[h][r] -> og_row[r][h] ----------------
__global__ __launch_bounds__(256) void k_transpose_og(const u16* __restrict__ src, u16* __restrict__ dst) {
  __shared__ u16 tile[64*TLD];  // 8448 B
  int bx = blockIdx.x;
  int h0 = (bx & 1) * 64;
  int r0 = (bx >> 1) * 64;
  int t = threadIdx.x;
  {
    int hh = t >> 2, seg = t & 3;
    const u16* gp = src + (size_t)(h0+hh)*M_ + r0 + seg*16;
    uint4 a = ((const uint4*)gp)[0];
    uint4 b = ((const uint4*)gp)[1];
    u32* lp = (u32*)(tile + hh*TLD + seg*16);
    lp[0]=a.x; lp[1]=a.y; lp[2]=a.z; lp[3]=a.w;
    lp[4]=b.x; lp[5]=b.y; lp[6]=b.z; lp[7]=b.w;
  }
  __syncthreads();
  {
    int r = t >> 2, q2 = t & 3;
    u32 outv[8];
    for (int s=0;s<8;s++) {
      int hh = q2*16 + 2*s;
      u32 lo = tile[hh*TLD + r];
      u32 hi = tile[(hh+1)*TLD + r];
      outv[s] = lo | (hi<<16);
    }
    u16* gp = dst + (size_t)(r0+r)*128 + h0 + q2*16;
    ((uint4*)gp)[0] = make_uint4(outv[0],outv[1],outv[2],outv[3]);
    ((uint4*)gp)[1] = make_uint4(outv[4],outv[5],outv[6],outv[7]);
  }
}

// ---------------- K3: og_row @ Wo + bo + pair, rowwise LN, fp32 out ----------------
#define LDW 72
__global__ __launch_bounds__(256) void k_final(const u16* __restrict__ og_row, const u16* __restrict__ wot,
    const float* __restrict__ pair, const float* __restrict__ bo,
    const float* __restrict__ ng, const float* __restrict__ nb_,
    float* __restrict__ out) {
  __shared__ u16 smem[2*128*LDW];  // 36864 B
  u16* At = smem; u16* Wt = smem + 128*LDW;
  int bx = blockIdx.x;
  int r0 = bx * 128;
  int t = threadIdx.x, w = t>>6, lane = t&63;
  int q = lane>>4, nl = lane&15;
  f32x4_t acc[2][8] = {};
  for (int c0 = 0; c0 < 128; c0 += 64) {
    { // stage A: og_row[r0+rr][c0 .. c0+63] — coalesced, vectorized
      int rr = t >> 1, half = t & 1;
      const u16* gp = og_row + (size_t)(r0+rr)*128 + c0 + half*32;
      u16* lp = At + rr*LDW + half*32;
      for (int i=0;i<4;i++) ((uint4*)lp)[i] = ((const uint4*)gp)[i];
    }
    { // stage Wo chunk: Wt[c][h']
      int c = t>>1, half = t&1;
      const u16* gp = wot + (size_t)c*128 + c0 + half*32;
      u16* lp = Wt + c*LDW + half*32;
      for (int i=0;i<4;i++) ((uint4*)lp)[i] = ((const uint4*)gp)[i];
    }
    __syncthreads();
    int mbase = w*32;
    for (int ks=0; ks<2; ks++) {
      int kel = ks*32 + q*8;
      bf16x8_t a[2], b[8];
      for (int tm=0;tm<2;tm++) a[tm] = *(const bf16x8_t*)(At + (mbase+tm*16+nl)*LDW + kel);
      for (int tn=0;tn<8;tn++) b[tn] = *(const bf16x8_t*)(Wt + (tn*16+nl)*LDW + kel);
      for (int tm=0;tm<2;tm++)
        for (int tn=0;tn<8;tn++)
          acc[tm][tn] = __builtin_amdgcn_mfma_f32_16x16x32_bf16(a[tm], b[tn], acc[tm][tn], 0,0,0);
    }
    __syncthreads();
  }
  // epilogue: residual + bias, transpose-free rowwise LN via 16-lane shfl reduction
  float rsum[2][4], rsq[2][4];
  for (int tm=0;tm<2;tm++) for (int p=0;p<4;p++) { rsum[tm][p]=0.f; rsq[tm][p]=0.f; }
  for (int tm=0;tm<2;tm++) for (int tn=0;tn<8;tn++) {
    int n = tn*16 + nl;
    float bb = bo[n];
    for (int p=0;p<4;p++) {
      int m = w*32 + tm*16 + q*4 + p;
      float v = acc[tm][tn][p] + bb + pair[(size_t)(r0+m)*128 + n];
      acc[tm][tn][p] = v;
      rsum[tm][p] += v;
      rsq[tm][p]  += v*v;
    }
  }
  for (int msk=1; msk<16; msk<<=1) {
    for (int tm=0;tm<2;tm++) for (int p=0;p<4;p++) {
      rsum[tm][p] += __shfl_xor(rsum[tm][p], msk, 64);
      rsq[tm][p]  += __shfl_xor(rsq[tm][p],  msk, 64);
    }
  }
  for (int tm=0;tm<2;tm++) for (int p=0;p<4;p++) {
    float mu = rsum[tm][p] * (1.f/128.f);
    float var = rsq[tm][p]*(1.f/128.f) - mu*mu;
    rsum[tm][p] = mu;
    rsq[tm][p] = rsqrtf(var + 1e-5f);
  }
  for (int tm=0;tm<2;tm++) for (int tn=0;tn<8;tn++) {
    int n = tn*16 + nl;
    float g = ng[n], b2 = nb_[n];
    for (int p=0;p<4;p++) {
      int m = w*32 + tm*16 + q*4 + p;
      out[(size_t)(r0+m)*128 + n] = (acc[tm][tn][p] - rsum[tm][p]) * rsq[tm][p] * g + b2;
    }
  }
}

extern "C" void kernel_launch(void* const* d_in, const int* in_sizes, int n_in,
                              void* d_out, int out_size, void* d_ws, size_t ws_size,
                              hipStream_t stream) {
  (void)in_sizes; (void)n_in; (void)out_size; (void)ws_size;
  const float* pair   = (const float*)d_in[0];
  const float* ln_l_g = (const float*)d_in[1];
  const float* ln_l_b = (const float*)d_in[2];
  const float* ln_r_g = (const float*)d_in[3];
  const float* ln_r_b = (const float*)d_in[4];
  const float* Wl = (const float*)d_in[5];
  const float* bl = (const float*)d_in[6];
  const float* Wr = (const float*)d_in[7];
  const float* br = (const float*)d_in[8];
  const float* Wg = (const float*)d_in[9];
  const float* bg = (const float*)d_in[10];
  const float* Wo = (const float*)d_in[11];
  const float* bo = (const float*)d_in[12];
  const float* n_g = (const float*)d_in[13];
  const float* n_b = (const float*)d_in[14];

  char* ws = (char*)d_ws;
  const size_t SZ = (size_t)M_*128*sizeof(u16);         // 37,748,736 B
  u16*  og_t    = (u16*)(ws);                           // written by k_einsum
  u16*  gate_t  = (u16*)(ws + SZ);
  u16*  right_t = (u16*)(ws + 2*SZ);                    // dead after k_transpose
  u16*  og_row  = (u16*)(ws + 2*SZ);                    // aliases right_t (written after einsum)
  u16*  wcat    = (u16*)(ws + 3*SZ);
  float* bcat   = (float*)(ws + 3*SZ + 98304);
  float* sgp    = (float*)(ws + 3*SZ + 98304 + 1536);
  u16*  wot     = (u16*)(ws + 3*SZ + 98304 + 1536 + 512);

  // left_t / right_tt live in d_out until k_final overwrites it with the result
  u16* left_t   = (u16*)d_out;
  u16* right_tt = (u16*)d_out + (size_t)M_*128;

  k_prep1<<<256, 256, 0, stream>>>(ln_l_g, ln_r_g, Wl, Wr, Wg, Wo, wcat, wot);
  k_prep2<<<2, 512, 0, stream>>>(ln_l_b, ln_r_b, Wl, Wr, Wg, bl, br, bg, bcat, sgp);
  k_projln<<<M_/128, 256, 0, stream>>>(pair, wcat, bcat, sgp, left_t, right_t, gate_t);
  k_transpose<<<4608, 256, 0, stream>>>(right_t, right_tt);
  k_einsum<<<1152, 256, 0, stream>>>(left_t, right_tt, gate_t, og_t);
  k_transpose_og<<<4608, 256, 0, stream>>>(og_t, og_row);
  k_final<<<1152, 256, 0, stream>>>(og_row, wot, pair, bo, n_g, n_b, (float*)d_out);
}

// Round 5
// 346.242 us; speedup vs baseline: 1.1493x; 1.0166x over previous
//
#include <hip/hip_runtime.h>
#include <hip/hip_bf16.h>

#define N_ 384
#define C_ 128
#define M_ (N_*N_)   // 147456 rows (i*384+j)

typedef __attribute__((ext_vector_type(8))) short bf16x8_t;
typedef __attribute__((ext_vector_type(4))) float f32x4_t;
typedef unsigned int u32;
typedef unsigned short u16;

__device__ __forceinline__ u16 f2bf(float f) {
  u32 u = __builtin_bit_cast(u32, f);
  u32 r = (u + 0x7FFFu + ((u >> 16) & 1u)) >> 16;
  return (u16)r;
}
__device__ __forceinline__ float bf2f(u16 h) {
  u32 u = ((u32)h) << 16;
  return __builtin_bit_cast(float, u);
}

// ---------------- prep kernels ----------------
__global__ __launch_bounds__(256) void k_prep1(const float* __restrict__ lg, const float* __restrict__ rg,
    const float* __restrict__ Wl, const float* __restrict__ Wr, const float* __restrict__ Wg,
    const float* __restrict__ Wo, u16* __restrict__ wcat, u16* __restrict__ wot) {
  int idx = blockIdx.x*256 + threadIdx.x;
  if (idx < 49152) {
    int n = idx >> 7, k = idx & 127;
    float v;
    if (n < 128)      v = lg[k] * Wl[k*128 + n];
    else if (n < 256) v = rg[k] * Wr[k*128 + (n-128)];
    else              v = Wg[k*128 + (n-256)];
    wcat[idx] = f2bf(v);
  } else {
    int i2 = idx - 49152;           // < 16384
    int c = i2 >> 7, h = i2 & 127;
    wot[i2] = f2bf(Wo[h*128 + c]);
  }
}

__global__ __launch_bounds__(512) void k_prep2(const float* __restrict__ lb, const float* __restrict__ rb,
    const float* __restrict__ Wl, const float* __restrict__ Wr, const float* __restrict__ Wg,
    const float* __restrict__ bl, const float* __restrict__ br, const float* __restrict__ bg,
    float* __restrict__ bcat, float* __restrict__ sg) {
  int t = threadIdx.x;
  if (blockIdx.x == 0) {
    if (t < 384) {
      float s = 0.f;
      if (t < 128)      { for (int k=0;k<128;k++) s += lb[k]*Wl[k*128+t];       s += bl[t];     }
      else if (t < 256) { int h=t-128; for (int k=0;k<128;k++) s += rb[k]*Wr[k*128+h]; s += br[h]; }
      else              { s = bg[t-256]; }
      bcat[t] = s;
    }
  } else {
    if (t < 128) {
      float s = 0.f;
      for (int k=0;k<128;k++) s += Wg[k*128+t];
      sg[t] = s;
    }
  }
}

#define LDK 136  // u16 stride of staged 128-k rows
#define LDA 72
#define LDW 72

// ---------------- K1: fused LN + one projection per block (nb-split) ----------------
// 3456 blocks = 3 nb x 1152 row-chunks. LN computed redundantly (pair re-reads are L2/L3-hot).
__global__ __launch_bounds__(256) void k_projln(const float* __restrict__ pair,
    const u16* __restrict__ wcat, const float* __restrict__ bcat, const float* __restrict__ sg,
    u16* __restrict__ left_t, u16* __restrict__ right_t, u16* __restrict__ gate_t) {
  __shared__ u16 At[128*LDK];   // 34816 B
  __shared__ u16 Tt[64*LDK];    // 17408 B
  __shared__ float mu_s[128];
  __shared__ float irs_s[128];
  int bx = blockIdx.x;
  int nb = bx % 3;
  int r0 = (bx / 3) * 128;
  int t = threadIdx.x, w = t>>6, lane = t&63;
  int q = lane>>4, nl = lane&15;

  // ---- LN phase: 2 threads per row ----
  {
    int rr = t >> 1, half = t & 1;
    const float4* gp = (const float4*)(pair + (size_t)(r0+rr)*128 + half*64);
    float4 v[16];
    #pragma unroll
    for (int i=0;i<16;i++) v[i] = gp[i];
    float s=0.f, qq=0.f;
    #pragma unroll
    for (int i=0;i<16;i++) {
      s  += v[i].x + v[i].y + v[i].z + v[i].w;
      qq += v[i].x*v[i].x + v[i].y*v[i].y + v[i].z*v[i].z + v[i].w*v[i].w;
    }
    s  += __shfl_xor(s, 1, 64);
    qq += __shfl_xor(qq, 1, 64);
    float mu = s * (1.f/128.f);
    float var = qq*(1.f/128.f) - mu*mu;
    float rstd = rsqrtf(var + 1e-5f);
    if (half == 0) { mu_s[rr] = mu; irs_s[rr] = 1.0f/rstd; }
    u32* lp = (u32*)(At + rr*LDK + half*64);
    #pragma unroll
    for (int i=0;i<8;i++) {
      u32 p0 = (u32)f2bf((v[2*i].x-mu)*rstd)   | ((u32)f2bf((v[2*i].y-mu)*rstd)<<16);
      u32 p1 = (u32)f2bf((v[2*i].z-mu)*rstd)   | ((u32)f2bf((v[2*i].w-mu)*rstd)<<16);
      u32 p2 = (u32)f2bf((v[2*i+1].x-mu)*rstd) | ((u32)f2bf((v[2*i+1].y-mu)*rstd)<<16);
      u32 p3 = (u32)f2bf((v[2*i+1].z-mu)*rstd) | ((u32)f2bf((v[2*i+1].w-mu)*rstd)<<16);
      ((uint4*)lp)[i] = make_uint4(p0,p1,p2,p3);
    }
  }
  __syncthreads();

  float muv[2][4], irv[2][4];
  #pragma unroll
  for (int tm=0;tm<2;tm++)
    #pragma unroll
    for (int p=0;p<4;p++) {
      int m = w*32 + tm*16 + q*4 + p;
      muv[tm][p] = mu_s[m];
      irv[tm][p] = irs_s[m];
    }

  f32x4_t acc[2][8] = {};
  const u16* bbase = wcat + (size_t)(nb*128)*128;
  #pragma unroll
  for (int ks=0; ks<4; ks++) {
    int kel = ks*32 + q*8;
    bf16x8_t a0 = *(const bf16x8_t*)(At + (w*32      + nl)*LDK + kel);
    bf16x8_t a1 = *(const bf16x8_t*)(At + (w*32 + 16 + nl)*LDK + kel);
    #pragma unroll
    for (int tn=0;tn<8;tn++) {
      bf16x8_t b = *(const bf16x8_t*)(bbase + (size_t)(tn*16+nl)*128 + kel);
      acc[0][tn] = __builtin_amdgcn_mfma_f32_16x16x32_bf16(a0, b, acc[0][tn], 0,0,0);
      acc[1][tn] = __builtin_amdgcn_mfma_f32_16x16x32_bf16(a1, b, acc[1][tn], 0,0,0);
    }
  }
  u16* dst = (nb==0) ? left_t : (nb==1) ? right_t : gate_t;
  for (int nhalf=0; nhalf<2; nhalf++) {
    #pragma unroll
    for (int tm=0;tm<2;tm++)
      #pragma unroll
      for (int tn4=0;tn4<4;tn4++) {
        int tn = nhalf*4 + tn4;
        int n = tn*16 + nl;
        float bias = bcat[nb*128 + n];
        float sgn = (nb==2) ? sg[n] : 0.f;
        f32x4_t a4 = acc[tm][tn];
        float o[4];
        #pragma unroll
        for (int p=0;p<4;p++) {
          float v = a4[p];
          if (nb == 2) {
            v = v*irv[tm][p] + muv[tm][p]*sgn + bias;
            v = 1.0f / (1.0f + __expf(-v));
          } else {
            v += bias;
          }
          o[p] = v;
        }
        int m = w*32 + tm*16 + q*4;
        u32* wp = (u32*)(Tt + (tn4*16+nl)*LDK + m);
        wp[0] = (u32)f2bf(o[0]) | ((u32)f2bf(o[1])<<16);
        wp[1] = (u32)f2bf(o[2]) | ((u32)f2bf(o[3])<<16);
      }
    __syncthreads();
    {
      // full row copy: 4 threads/row x 32 u16 (4x uint4) = 128 u16 per row
      int nr = t>>2, q4 = t&3;
      const uint4* lp = (const uint4*)(Tt + nr*LDK + q4*32);
      u16* gp = dst + (size_t)(nhalf*64+nr)*M_ + r0 + q4*32;
      ((uint4*)gp)[0] = lp[0];
      ((uint4*)gp)[1] = lp[1];
      ((uint4*)gp)[2] = lp[2];
      ((uint4*)gp)[3] = lp[3];
    }
    __syncthreads();
  }
}

// ---------------- K2: triangle einsum per h + gate multiply ----------------
// B staged from right_t[h][k][j] with in-LDS transpose (no separate transpose kernel).
__global__ __launch_bounds__(256) void k_einsum(const u16* __restrict__ left_t, const u16* __restrict__ right_t,
    const u16* __restrict__ gate_t, u16* __restrict__ og_t) {
  __shared__ u16 smem[2*128*LDA];  // 36864 B
  u16* At = smem; u16* Bt = smem + 128*LDA;
  int bx = blockIdx.x;
  int h = bx / 9; int rem = bx % 9;
  int i0 = (rem/3)*128, j0 = (rem%3)*128;
  const u16* Ag = left_t + (size_t)h*M_;
  const u16* Bg = right_t + (size_t)h*M_;
  int t = threadIdx.x, w = t>>6, lane = t&63;
  int q = lane>>4, nl = lane&15;
  f32x4_t acc[4][4] = {};
  int m0 = (w&1)*64, n0 = (w>>1)*64;
  for (int kb = 0; kb < N_; kb += 64) {
    { // stage A: left_t rows (i), k contiguous — direct vector copy
      int rr = t>>1, half = t&1;
      const u16* gp = Ag + (size_t)(i0+rr)*N_ + kb + half*32;
      u16* lp = At + rr*LDA + half*32;
      #pragma unroll
      for (int i=0;i<4;i++) ((uint4*)lp)[i] = ((const uint4*)gp)[i];
    }
    { // stage B with transpose: right_t[(kb+kk)*384 + j0+j] -> Bt[j][kk]
      int kk = t>>2, seg = t&3;
      const u16* gq = Bg + (size_t)(kb+kk)*N_ + j0 + seg*32;
      uint4 bb[4];
      #pragma unroll
      for (int i=0;i<4;i++) bb[i] = ((const uint4*)gq)[i];
      #pragma unroll
      for (int i=0;i<4;i++) {
        int jb = seg*32 + i*8;
        u32 x0=bb[i].x, x1=bb[i].y, x2=bb[i].z, x3=bb[i].w;
        Bt[(jb+0)*LDA+kk] = (u16)(x0&0xffffu); Bt[(jb+1)*LDA+kk] = (u16)(x0>>16);
        Bt[(jb+2)*LDA+kk] = (u16)(x1&0xffffu); Bt[(jb+3)*LDA+kk] = (u16)(x1>>16);
        Bt[(jb+4)*LDA+kk] = (u16)(x2&0xffffu); Bt[(jb+5)*LDA+kk] = (u16)(x2>>16);
        Bt[(jb+6)*LDA+kk] = (u16)(x3&0xffffu); Bt[(jb+7)*LDA+kk] = (u16)(x3>>16);
      }
    }
    __syncthreads();
    for (int ks=0; ks<2; ks++) {
      int kel = ks*32 + q*8;
      bf16x8_t a[4], b[4];
      #pragma unroll
      for (int tm=0;tm<4;tm++) a[tm] = *(const bf16x8_t*)(At + (m0+tm*16+nl)*LDA + kel);
      #pragma unroll
      for (int tn=0;tn<4;tn++) b[tn] = *(const bf16x8_t*)(Bt + (n0+tn*16+nl)*LDA + kel);
      #pragma unroll
      for (int tm=0;tm<4;tm++)
        #pragma unroll
        for (int tn=0;tn<4;tn++)
          acc[tm][tn] = __builtin_amdgcn_mfma_f32_16x16x32_bf16(a[tm], b[tn], acc[tm][tn], 0,0,0);
    }
    __syncthreads();
  }
  // epilogue: acc -> LDS bf16 [m][n], then gate-multiplied coalesced store (og_t[h][r])
#define LDT 136
  u16* Ot = smem;  // 128*LDT u16 = 34816 B <= 36864
  #pragma unroll
  for (int tm=0;tm<4;tm++)
    #pragma unroll
    for (int tn=0;tn<4;tn++)
      #pragma unroll
      for (int p=0;p<4;p++) {
        int m = m0 + tm*16 + q*4 + p;
        int n = n0 + tn*16 + nl;
        Ot[m*LDT + n] = f2bf(acc[tm][tn][p]);
      }
  __syncthreads();
  {
    int m = t>>1, half = t&1;
    size_t rbase = (size_t)h*M_ + (size_t)(i0+m)*N_ + j0 + half*64;
    const uint4* gg = (const uint4*)(gate_t + rbase);
    const uint4* lo = (const uint4*)(Ot + m*LDT + half*64);
    uint4* od = (uint4*)(og_t + rbase);
    #pragma unroll
    for (int i=0;i<8;i++) {
      uint4 gv = gg[i]; uint4 ov = lo[i];
      u32 ga[4] = {gv.x,gv.y,gv.z,gv.w};
      u32 oa[4] = {ov.x,ov.y,ov.z,ov.w};
      u32 ra[4];
      #pragma unroll
      for (int e=0;e<4;e++) {
        float g0 = bf2f((u16)(ga[e]&0xffffu)), g1 = bf2f((u16)(ga[e]>>16));
        float o0 = bf2f((u16)(oa[e]&0xffffu)), o1 = bf2f((u16)(oa[e]>>16));
        ra[e] = (u32)f2bf(o0*g0) | ((u32)f2bf(o1*g1)<<16);
      }
      od[i] = make_uint4(ra[0],ra[1],ra[2],ra[3]);
    }
  }
}

// ---------------- K3: og @ Wo + bo + pair, rowwise LN, fp32 out ----------------
// A staged from og_t[h][r] with in-LDS transpose (no separate transpose kernel).
__global__ __launch_bounds__(256) void k_final(const u16* __restrict__ og_t, const u16* __restrict__ wot,
    const float* __restrict__ pair, const float* __restrict__ bo,
    const float* __restrict__ ng, const float* __restrict__ nb_,
    float* __restrict__ out) {
  __shared__ u16 smem[2*128*LDW];  // 36864 B
  u16* At = smem; u16* Wt = smem + 128*LDW;
  int bx = blockIdx.x;
  int r0 = bx * 128;
  int t = threadIdx.x, w = t>>6, lane = t&63;
  int q = lane>>4, nl = lane&15;
  f32x4_t acc[2][8] = {};
  for (int c0 = 0; c0 < 128; c0 += 64) {
    { // stage A with transpose: og_t[(c0+hh)*M + r0+r] -> At[r][hh]
      int hh = t>>2, seg = t&3;
      const u16* gp = og_t + (size_t)(c0+hh)*M_ + r0 + seg*32;
      uint4 bb[4];
      #pragma unroll
      for (int i=0;i<4;i++) bb[i] = ((const uint4*)gp)[i];
      #pragma unroll
      for (int i=0;i<4;i++) {
        int rb = seg*32 + i*8;
        u32 x0=bb[i].x, x1=bb[i].y, x2=bb[i].z, x3=bb[i].w;
        At[(rb+0)*LDW+hh] = (u16)(x0&0xffffu); At[(rb+1)*LDW+hh] = (u16)(x0>>16);
        At[(rb+2)*LDW+hh] = (u16)(x1&0xffffu); At[(rb+3)*LDW+hh] = (u16)(x1>>16);
        At[(rb+4)*LDW+hh] = (u16)(x2&0xffffu); At[(rb+5)*LDW+hh] = (u16)(x2>>16);
        At[(rb+6)*LDW+hh] = (u16)(x3&0xffffu); At[(rb+7)*LDW+hh] = (u16)(x3>>16);
      }
    }
    { // stage Wo chunk: Wt[c][h']
      int c = t>>1, half = t&1;
      const u16* gp = wot + (size_t)c*128 + c0 + half*32;
      u16* lp = Wt + c*LDW + half*32;
      #pragma unroll
      for (int i=0;i<4;i++) ((uint4*)lp)[i] = ((const uint4*)gp)[i];
    }
    __syncthreads();
    int mbase = w*32;
    for (int ks=0; ks<2; ks++) {
      int kel = ks*32 + q*8;
      bf16x8_t a[2], b[8];
      #pragma unroll
      for (int tm=0;tm<2;tm++) a[tm] = *(const bf16x8_t*)(At + (mbase+tm*16+nl)*LDW + kel);
      #pragma unroll
      for (int tn=0;tn<8;tn++) b[tn] = *(const bf16x8_t*)(Wt + (tn*16+nl)*LDW + kel);
      #pragma unroll
      for (int tm=0;tm<2;tm++)
        #pragma unroll
        for (int tn=0;tn<8;tn++)
          acc[tm][tn] = __builtin_amdgcn_mfma_f32_16x16x32_bf16(a[tm], b[tn], acc[tm][tn], 0,0,0);
    }
    __syncthreads();
  }
  // epilogue: residual + bias, transpose-free rowwise LN via 16-lane shfl reduction
  float rsum[2][4], rsq[2][4];
  for (int tm=0;tm<2;tm++) for (int p=0;p<4;p++) { rsum[tm][p]=0.f; rsq[tm][p]=0.f; }
  #pragma unroll
  for (int tm=0;tm<2;tm++)
    #pragma unroll
    for (int tn=0;tn<8;tn++) {
      int n = tn*16 + nl;
      float bb = bo[n];
      #pragma unroll
      for (int p=0;p<4;p++) {
        int m = w*32 + tm*16 + q*4 + p;
        float v = acc[tm][tn][p] + bb + pair[(size_t)(r0+m)*128 + n];
        acc[tm][tn][p] = v;
        rsum[tm][p] += v;
        rsq[tm][p]  += v*v;
      }
    }
  for (int msk=1; msk<16; msk<<=1) {
    #pragma unroll
    for (int tm=0;tm<2;tm++)
      #pragma unroll
      for (int p=0;p<4;p++) {
        rsum[tm][p] += __shfl_xor(rsum[tm][p], msk, 64);
        rsq[tm][p]  += __shfl_xor(rsq[tm][p],  msk, 64);
      }
  }
  #pragma unroll
  for (int tm=0;tm<2;tm++)
    #pragma unroll
    for (int p=0;p<4;p++) {
      float mu = rsum[tm][p] * (1.f/128.f);
      float var = rsq[tm][p]*(1.f/128.f) - mu*mu;
      rsum[tm][p] = mu;
      rsq[tm][p] = rsqrtf(var + 1e-5f);
    }
  #pragma unroll
  for (int tm=0;tm<2;tm++)
    #pragma unroll
    for (int tn=0;tn<8;tn++) {
      int n = tn*16 + nl;
      float g = ng[n], b2 = nb_[n];
      #pragma unroll
      for (int p=0;p<4;p++) {
        int m = w*32 + tm*16 + q*4 + p;
        out[(size_t)(r0+m)*128 + n] = (acc[tm][tn][p] - rsum[tm][p]) * rsq[tm][p] * g + b2;
      }
    }
}

extern "C" void kernel_launch(void* const* d_in, const int* in_sizes, int n_in,
                              void* d_out, int out_size, void* d_ws, size_t ws_size,
                              hipStream_t stream) {
  (void)in_sizes; (void)n_in; (void)out_size; (void)ws_size;
  const float* pair   = (const float*)d_in[0];
  const float* ln_l_g = (const float*)d_in[1];
  const float* ln_l_b = (const float*)d_in[2];
  const float* ln_r_g = (const float*)d_in[3];
  const float* ln_r_b = (const float*)d_in[4];
  const float* Wl = (const float*)d_in[5];
  const float* bl = (const float*)d_in[6];
  const float* Wr = (const float*)d_in[7];
  const float* br = (const float*)d_in[8];
  const float* Wg = (const float*)d_in[9];
  const float* bg = (const float*)d_in[10];
  const float* Wo = (const float*)d_in[11];
  const float* bo = (const float*)d_in[12];
  const float* n_g = (const float*)d_in[13];
  const float* n_b = (const float*)d_in[14];

  char* ws = (char*)d_ws;
  const size_t SZ = (size_t)M_*128*sizeof(u16);         // 37,748,736 B
  u16*  og_t    = (u16*)(ws);                           // written by k_einsum
  u16*  gate_t  = (u16*)(ws + SZ);
  u16*  wcat    = (u16*)(ws + 2*SZ);
  float* bcat   = (float*)(ws + 2*SZ + 98304);
  float* sgp    = (float*)(ws + 2*SZ + 98304 + 1536);
  u16*  wot     = (u16*)(ws + 2*SZ + 98304 + 1536 + 512);

  // left_t / right_t live in d_out until k_final overwrites it with the result
  u16* left_t   = (u16*)d_out;
  u16* right_t  = (u16*)d_out + (size_t)M_*128;

  k_prep1<<<256, 256, 0, stream>>>(ln_l_g, ln_r_g, Wl, Wr, Wg, Wo, wcat, wot);
  k_prep2<<<2, 512, 0, stream>>>(ln_l_b, ln_r_b, Wl, Wr, Wg, bl, br, bg, bcat, sgp);
  k_projln<<<3456, 256, 0, stream>>>(pair, wcat, bcat, sgp, left_t, right_t, gate_t);
  k_einsum<<<1152, 256, 0, stream>>>(left_t, right_t, gate_t, og_t);
  k_final<<<1152, 256, 0, stream>>>(og_t, wot, pair, bo, n_g, n_b, (float*)d_out);
}